// Round 6
// baseline (754.450 us; speedup 1.0000x reference)
//
#include <hip/hip_runtime.h>

// ---------------------------------------------------------------------------
// Drug-path-only GNN (gene path is dead code w.r.t. outputs).
// Round 6: edge-chunk-partitioned CSR build. Round-5 profile: dst-range
// partitioning read the edge list 8x (FETCH 46.6MB) which thrashed L2 and
// still left 54MB of partial-line writebacks. Now each XCD (blockIdx&7)
// owns a contiguous 1/8 of the EDGES and builds private per-partition CSR
// segments (partition-major layout): reads 1x, writes land in an
// XCD-private 750KB region -> full-line accumulation in its L2.
// Gather loops the 8 sub-segments per node; degree = sum of segment sizes.
// ---------------------------------------------------------------------------

#define NPART 8

// out[m][n] = sum_k A[m][k]*W[k][n]; KOUT==64; weights in VGPRs (col per lane)
template<int KIN>
__global__ __launch_bounds__(256) void gemm_reg_kernel(const float* __restrict__ A,
                                                       const float* __restrict__ W,
                                                       float* __restrict__ out, int M) {
    const int lane = threadIdx.x & 63;
    const int gwave = blockIdx.x * (blockDim.x >> 6) + (threadIdx.x >> 6);
    const int nwave = gridDim.x * (blockDim.x >> 6);
    float w[KIN];
#pragma unroll
    for (int k = 0; k < KIN; ++k) w[k] = W[k * 64 + lane];   // coalesced, once
    for (int m0 = gwave * 2; m0 < M; m0 += nwave * 2) {
        const int mu = __builtin_amdgcn_readfirstlane(m0);   // force uniform
        const float* a0 = A + (size_t)mu * KIN;
        const float* a1 = a0 + KIN;
        const bool two = (mu + 1) < M;
        float acc0 = 0.0f, acc1 = 0.0f;
#pragma unroll
        for (int k = 0; k < KIN; ++k) {
            const float av0 = a0[k];
            const float av1 = two ? a1[k] : 0.0f;
            acc0 = fmaf(av0, w[k], acc0);
            acc1 = fmaf(av1, w[k], acc1);
        }
        out[(size_t)mu * 64 + lane] = acc0;
        if (two) out[(size_t)(mu + 1) * 64 + lane] = acc1;
    }
}

// layer-2 pair: KIN=64, KOUT=32. Lanes 0..31 -> Wa cols, lanes 32..63 -> Wb.
__global__ __launch_bounds__(256) void gemm2_reg_kernel(const float* __restrict__ A,
                                                        const float* __restrict__ Wa,
                                                        const float* __restrict__ Wb,
                                                        float* __restrict__ out_a,
                                                        float* __restrict__ out_b, int M) {
    const int lane = threadIdx.x & 63;
    const int col = lane & 31;
    const float* Wm = (lane < 32) ? Wa : Wb;
    float* om = (lane < 32) ? out_a : out_b;
    const int gwave = blockIdx.x * (blockDim.x >> 6) + (threadIdx.x >> 6);
    const int nwave = gridDim.x * (blockDim.x >> 6);
    float w[64];
#pragma unroll
    for (int k = 0; k < 64; ++k) w[k] = Wm[k * 32 + col];
    for (int m0 = gwave * 2; m0 < M; m0 += nwave * 2) {
        const int mu = __builtin_amdgcn_readfirstlane(m0);
        const float* a0 = A + (size_t)mu * 64;
        const float* a1 = a0 + 64;
        const bool two = (mu + 1) < M;
        float acc0 = 0.0f, acc1 = 0.0f;
#pragma unroll
        for (int k = 0; k < 64; ++k) {
            const float av0 = a0[k];
            const float av1 = two ? a1[k] : 0.0f;
            acc0 = fmaf(av0, w[k], acc0);
            acc1 = fmaf(av1, w[k], acc1);
        }
        om[(size_t)mu * 32 + col] = acc0;
        if (two) om[(size_t)(mu + 1) * 32 + col] = acc1;
    }
}

// per-edge-chunk degree histogram into partition-private deg8[p][n]
__global__ __launch_bounds__(256) void degree8_kernel(const int* __restrict__ dst,
                                                      int* __restrict__ deg8,
                                                      int E, int chunk, int N) {
    const int p = blockIdx.x & (NPART - 1);
    const int lo = p * chunk;
    const int hi = min(lo + chunk, E);
    int* __restrict__ deg = deg8 + (size_t)p * N;
    const int bip = blockIdx.x >> 3;
    const int stride = (gridDim.x >> 3) * 256;
    for (int e = lo + bip * 256 + threadIdx.x; e < hi; e += stride)
        atomicAdd(&deg[dst[e]], 1);
}

// single-block exclusive scan over M8 elements; writes off8[0..M8], cursor8=off8
__global__ __launch_bounds__(1024) void scan_kernel(const int* __restrict__ deg,
                                                    int* __restrict__ off,
                                                    int* __restrict__ cursor, int M8) {
    __shared__ int part[1024];
    const int t = threadIdx.x;
    const int per = (M8 + 1023) / 1024;
    const int beg = t * per;
    const int end = min(beg + per, M8);
    int s = 0;
    for (int i = beg; i < end; ++i) s += deg[i];
    part[t] = s;
    __syncthreads();
    for (int d = 1; d < 1024; d <<= 1) {
        int v = (t >= d) ? part[t - d] : 0;
        __syncthreads();
        part[t] += v;
        __syncthreads();
    }
    int run = (t == 0) ? 0 : part[t - 1];
    for (int i = beg; i < end; ++i) { off[i] = run; cursor[i] = run; run += deg[i]; }
    if (t == 1023) off[M8] = part[1023];
}

// edge-chunk-partitioned bucket fill into partition-private CSR segments
__global__ __launch_bounds__(256) void fill8_kernel(const int* __restrict__ src,
                                                    const int* __restrict__ dst,
                                                    int* __restrict__ cursor8,
                                                    int* __restrict__ csr_src,
                                                    int E, int chunk, int N) {
    const int p = blockIdx.x & (NPART - 1);
    const int lo = p * chunk;
    const int hi = min(lo + chunk, E);
    int* __restrict__ cursor = cursor8 + (size_t)p * N;
    const int bip = blockIdx.x >> 3;
    const int stride = (gridDim.x >> 3) * 256;
    for (int e = lo + bip * 256 + threadIdx.x; e < hi; e += stride) {
        const int d = dst[e];
        const int s = src[e];
        const int pos = atomicAdd(&cursor[d], 1);
        csr_src[pos] = s;
    }
}

// One W-lane group per dst node: loop 8 partition sub-segments, register-
// accumulate, fused mean+self+bias(+relu).
template<int W, bool RELU>
__global__ __launch_bounds__(256) void gather_combine_kernel(
        const float* __restrict__ msg, const int* __restrict__ csr_src,
        const int* __restrict__ off8, const int* __restrict__ end8,
        const float* __restrict__ selfb, const float* __restrict__ b,
        float* __restrict__ out, int N) {
    const int GRP = 256 / W;
    const int g = threadIdx.x / W;
    const int lane = threadIdx.x % W;
    const float bk = b[lane];
    for (int n = blockIdx.x * GRP + g; n < N; n += gridDim.x * GRP) {
        float acc = 0.0f;
        int cnt = 0;
        for (int p = 0; p < NPART; ++p) {
            const int beg = off8[(size_t)p * N + n];
            const int end = end8[(size_t)p * N + n];
            cnt += end - beg;
            int i = beg;
            for (; i + 4 <= end; i += 4) {
                const int s0 = csr_src[i], s1 = csr_src[i + 1];
                const int s2 = csr_src[i + 2], s3 = csr_src[i + 3];
                const float v0 = msg[(size_t)s0 * W + lane];
                const float v1 = msg[(size_t)s1 * W + lane];
                const float v2 = msg[(size_t)s2 * W + lane];
                const float v3 = msg[(size_t)s3 * W + lane];
                acc += (v0 + v1) + (v2 + v3);
            }
            for (; i < end; ++i) acc += msg[(size_t)csr_src[i] * W + lane];
        }
        const float d = (cnt > 0) ? (float)cnt : 1.0f;
        float v = acc / d + selfb[(size_t)n * W + lane] + bk;
        if (RELU) v = fmaxf(v, 0.0f);
        out[(size_t)n * W + lane] = v;
    }
}

// fused pos+neg scorer: 8 lanes per edge, float4 slices of 32-wide h rows
__global__ __launch_bounds__(256) void score2_kernel(const float* __restrict__ h,
                                                     const int* __restrict__ sA,
                                                     const int* __restrict__ dA,
                                                     const int* __restrict__ sB,
                                                     const int* __restrict__ dB,
                                                     const float* __restrict__ wrel,
                                                     float* __restrict__ outA,
                                                     float* __restrict__ outB,
                                                     int EA, int EB) {
    const int lj = threadIdx.x & 7;
    const size_t grp = ((size_t)blockIdx.x * blockDim.x + threadIdx.x) >> 3;
    const size_t ngrp = ((size_t)gridDim.x * blockDim.x) >> 3;
    const float4 w = *(const float4*)(wrel + lj * 4);
    const size_t total = (size_t)EA + (size_t)EB;
    for (size_t e = grp; e < total; e += ngrp) {
        int s, d; float* o;
        if (e < (size_t)EA) { s = sA[e]; d = dA[e]; o = outA + e; }
        else { const size_t e2 = e - EA; s = sB[e2]; d = dB[e2]; o = outB + e2; }
        const float4 hs = *(const float4*)(h + (size_t)s * 32 + lj * 4);
        const float4 hd = *(const float4*)(h + (size_t)d * 32 + lj * 4);
        float p = hs.x * w.x * hd.x + hs.y * w.y * hd.y +
                  hs.z * w.z * hd.z + hs.w * w.w * hd.w;
        p += __shfl_xor(p, 1, 64);
        p += __shfl_xor(p, 2, 64);
        p += __shfl_xor(p, 4, 64);
        if (lj == 0) *o = p;
    }
}

extern "C" void kernel_launch(void* const* d_in, const int* in_sizes, int n_in,
                              void* d_out, int out_size, void* d_ws, size_t ws_size,
                              hipStream_t stream) {
    const float* feat_drug    = (const float*)d_in[0];
    const int*   dd_src       = (const int*)d_in[2];
    const int*   dd_dst       = (const int*)d_in[3];
    const int*   neg_src      = (const int*)d_in[8];
    const int*   neg_dst      = (const int*)d_in[9];
    const float* W1_dd        = (const float*)d_in[10];
    const float* W1_self_drug = (const float*)d_in[13];
    const float* b1           = (const float*)d_in[15];
    const float* W2_dd        = (const float*)d_in[16];
    const float* W2_self_drug = (const float*)d_in[19];
    const float* b2           = (const float*)d_in[21];
    const float* w_rel        = (const float*)d_in[22];

    const int N  = in_sizes[0] / 128;  // 20000 drugs
    const int E  = in_sizes[2];        // 1.5M dd edges
    const int EN = in_sizes[8];        // 1.5M neg edges
    const int CHUNK = (E + NPART - 1) / NPART;
    const int M8 = NPART * N;

    // workspace layout (4-byte elements)
    char* ws = (char*)d_ws;
    int*   deg8    = (int*)ws;                         ws += (size_t)M8 * 4;
    int*   off8    = (int*)ws;                         ws += (size_t)(M8 + 1) * 4;
    int*   cursor8 = (int*)ws;                         ws += (size_t)M8 * 4;
    int*   csr_src = (int*)ws;                         ws += (size_t)E * 4;
    float* msg1    = (float*)ws;                       ws += (size_t)N * 64 * 4;
    float* self1   = (float*)ws;                       ws += (size_t)N * 64 * 4;
    float* h1      = (float*)ws;                       ws += (size_t)N * 64 * 4;
    float* msg2    = (float*)ws;                       ws += (size_t)N * 32 * 4;
    float* self2   = (float*)ws;                       ws += (size_t)N * 32 * 4;
    float* h2      = (float*)ws;                       ws += (size_t)N * 32 * 4;

    float* pos = (float*)d_out;
    float* neg = pos + E;

    hipMemsetAsync(deg8, 0, (size_t)M8 * sizeof(int), stream);

    // ---- CSR-by-dst build (edge-chunk partitioned, XCD-private regions) ----
    degree8_kernel<<<1024, 256, 0, stream>>>(dd_dst, deg8, E, CHUNK, N);
    scan_kernel<<<1, 1024, 0, stream>>>(deg8, off8, cursor8, M8);
    fill8_kernel<<<1024, 256, 0, stream>>>(dd_src, dd_dst, cursor8, csr_src, E, CHUNK, N);

    // ---- layer 1: register-weight GEMMs (no LDS) ----
    gemm_reg_kernel<128><<<512, 256, 0, stream>>>(feat_drug, W1_dd, msg1, N);
    gemm_reg_kernel<128><<<512, 256, 0, stream>>>(feat_drug, W1_self_drug, self1, N);
    gather_combine_kernel<64, true><<<(N + 3) / 4, 256, 0, stream>>>(
        msg1, csr_src, off8, cursor8, self1, b1, h1, N);

    // ---- layer 2: fused dual-matrix register GEMM ----
    gemm2_reg_kernel<<<512, 256, 0, stream>>>(h1, W2_dd, W2_self_drug, msg2, self2, N);
    gather_combine_kernel<32, false><<<(N + 7) / 8, 256, 0, stream>>>(
        msg2, csr_src, off8, cursor8, self2, b2, h2, N);

    // ---- scorer (pos + neg fused) ----
    score2_kernel<<<4096, 256, 0, stream>>>(h2, dd_src, dd_dst, neg_src, neg_dst,
                                            w_rel, pos, neg, E, EN);
}

// Round 7
// 407.954 us; speedup vs baseline: 1.8494x; 1.8494x over previous
//
#include <hip/hip_runtime.h>

// ---------------------------------------------------------------------------
// Drug-path-only GNN (gene path is dead code w.r.t. outputs).
// Round 7: fix the scan. Round-6's single-block scan over 8*N=160K elements
// ran at 0.15% occupancy for 369us (latency-bound serial section). Key
// insight: partition p's CSR region base is statically p*CHUNK (its segment
// total == its edge-chunk size), so no cross-partition scan is needed --
// 8 independent within-partition scans, one block each (scan8_kernel<<<8>>>).
// ---------------------------------------------------------------------------

#define NPART 8

// out[m][n] = sum_k A[m][k]*W[k][n]; KOUT==64; weights in VGPRs (col per lane)
template<int KIN>
__global__ __launch_bounds__(256) void gemm_reg_kernel(const float* __restrict__ A,
                                                       const float* __restrict__ W,
                                                       float* __restrict__ out, int M) {
    const int lane = threadIdx.x & 63;
    const int gwave = blockIdx.x * (blockDim.x >> 6) + (threadIdx.x >> 6);
    const int nwave = gridDim.x * (blockDim.x >> 6);
    float w[KIN];
#pragma unroll
    for (int k = 0; k < KIN; ++k) w[k] = W[k * 64 + lane];   // coalesced, once
    for (int m0 = gwave * 2; m0 < M; m0 += nwave * 2) {
        const int mu = __builtin_amdgcn_readfirstlane(m0);   // force uniform
        const float* a0 = A + (size_t)mu * KIN;
        const float* a1 = a0 + KIN;
        const bool two = (mu + 1) < M;
        float acc0 = 0.0f, acc1 = 0.0f;
#pragma unroll
        for (int k = 0; k < KIN; ++k) {
            const float av0 = a0[k];
            const float av1 = two ? a1[k] : 0.0f;
            acc0 = fmaf(av0, w[k], acc0);
            acc1 = fmaf(av1, w[k], acc1);
        }
        out[(size_t)mu * 64 + lane] = acc0;
        if (two) out[(size_t)(mu + 1) * 64 + lane] = acc1;
    }
}

// layer-2 pair: KIN=64, KOUT=32. Lanes 0..31 -> Wa cols, lanes 32..63 -> Wb.
__global__ __launch_bounds__(256) void gemm2_reg_kernel(const float* __restrict__ A,
                                                        const float* __restrict__ Wa,
                                                        const float* __restrict__ Wb,
                                                        float* __restrict__ out_a,
                                                        float* __restrict__ out_b, int M) {
    const int lane = threadIdx.x & 63;
    const int col = lane & 31;
    const float* Wm = (lane < 32) ? Wa : Wb;
    float* om = (lane < 32) ? out_a : out_b;
    const int gwave = blockIdx.x * (blockDim.x >> 6) + (threadIdx.x >> 6);
    const int nwave = gridDim.x * (blockDim.x >> 6);
    float w[64];
#pragma unroll
    for (int k = 0; k < 64; ++k) w[k] = Wm[k * 32 + col];
    for (int m0 = gwave * 2; m0 < M; m0 += nwave * 2) {
        const int mu = __builtin_amdgcn_readfirstlane(m0);
        const float* a0 = A + (size_t)mu * 64;
        const float* a1 = a0 + 64;
        const bool two = (mu + 1) < M;
        float acc0 = 0.0f, acc1 = 0.0f;
#pragma unroll
        for (int k = 0; k < 64; ++k) {
            const float av0 = a0[k];
            const float av1 = two ? a1[k] : 0.0f;
            acc0 = fmaf(av0, w[k], acc0);
            acc1 = fmaf(av1, w[k], acc1);
        }
        om[(size_t)mu * 32 + col] = acc0;
        if (two) om[(size_t)(mu + 1) * 32 + col] = acc1;
    }
}

// per-edge-chunk degree histogram into partition-private deg8[p][n]
__global__ __launch_bounds__(256) void degree8_kernel(const int* __restrict__ dst,
                                                      int* __restrict__ deg8,
                                                      int E, int chunk, int N) {
    const int p = blockIdx.x & (NPART - 1);
    const int lo = p * chunk;
    const int hi = min(lo + chunk, E);
    int* __restrict__ deg = deg8 + (size_t)p * N;
    const int bip = blockIdx.x >> 3;
    const int stride = (gridDim.x >> 3) * 256;
    for (int e = lo + bip * 256 + threadIdx.x; e < hi; e += stride)
        atomicAdd(&deg[dst[e]], 1);
}

// 8 independent within-partition scans; block p scans deg8[p][0..N) with
// base offset p*chunk (partition segment sizes are statically known).
__global__ __launch_bounds__(1024) void scan8_kernel(const int* __restrict__ deg8,
                                                     int* __restrict__ off8,
                                                     int* __restrict__ cursor8,
                                                     int N, int chunk) {
    const int p = blockIdx.x;
    const int base = p * chunk;
    const int* __restrict__ deg = deg8 + (size_t)p * N;
    int* __restrict__ off = off8 + (size_t)p * N;
    int* __restrict__ cur = cursor8 + (size_t)p * N;
    __shared__ int part[1024];
    const int t = threadIdx.x;
    const int per = (N + 1023) / 1024;
    const int beg = t * per;
    const int end = min(beg + per, N);
    int s = 0;
    for (int i = beg; i < end; ++i) s += deg[i];
    part[t] = s;
    __syncthreads();
    for (int d = 1; d < 1024; d <<= 1) {
        int v = (t >= d) ? part[t - d] : 0;
        __syncthreads();
        part[t] += v;
        __syncthreads();
    }
    int run = base + ((t == 0) ? 0 : part[t - 1]);
    for (int i = beg; i < end; ++i) { off[i] = run; cur[i] = run; run += deg[i]; }
}

// edge-chunk-partitioned bucket fill into partition-private CSR segments
__global__ __launch_bounds__(256) void fill8_kernel(const int* __restrict__ src,
                                                    const int* __restrict__ dst,
                                                    int* __restrict__ cursor8,
                                                    int* __restrict__ csr_src,
                                                    int E, int chunk, int N) {
    const int p = blockIdx.x & (NPART - 1);
    const int lo = p * chunk;
    const int hi = min(lo + chunk, E);
    int* __restrict__ cursor = cursor8 + (size_t)p * N;
    const int bip = blockIdx.x >> 3;
    const int stride = (gridDim.x >> 3) * 256;
    for (int e = lo + bip * 256 + threadIdx.x; e < hi; e += stride) {
        const int d = dst[e];
        const int s = src[e];
        const int pos = atomicAdd(&cursor[d], 1);
        csr_src[pos] = s;
    }
}

// One W-lane group per dst node: loop 8 partition sub-segments, register-
// accumulate, fused mean+self+bias(+relu).
template<int W, bool RELU>
__global__ __launch_bounds__(256) void gather_combine_kernel(
        const float* __restrict__ msg, const int* __restrict__ csr_src,
        const int* __restrict__ off8, const int* __restrict__ end8,
        const float* __restrict__ selfb, const float* __restrict__ b,
        float* __restrict__ out, int N) {
    const int GRP = 256 / W;
    const int g = threadIdx.x / W;
    const int lane = threadIdx.x % W;
    const float bk = b[lane];
    for (int n = blockIdx.x * GRP + g; n < N; n += gridDim.x * GRP) {
        float acc = 0.0f;
        int cnt = 0;
        for (int p = 0; p < NPART; ++p) {
            const int beg = off8[(size_t)p * N + n];
            const int end = end8[(size_t)p * N + n];
            cnt += end - beg;
            int i = beg;
            for (; i + 4 <= end; i += 4) {
                const int s0 = csr_src[i], s1 = csr_src[i + 1];
                const int s2 = csr_src[i + 2], s3 = csr_src[i + 3];
                const float v0 = msg[(size_t)s0 * W + lane];
                const float v1 = msg[(size_t)s1 * W + lane];
                const float v2 = msg[(size_t)s2 * W + lane];
                const float v3 = msg[(size_t)s3 * W + lane];
                acc += (v0 + v1) + (v2 + v3);
            }
            for (; i < end; ++i) acc += msg[(size_t)csr_src[i] * W + lane];
        }
        const float d = (cnt > 0) ? (float)cnt : 1.0f;
        float v = acc / d + selfb[(size_t)n * W + lane] + bk;
        if (RELU) v = fmaxf(v, 0.0f);
        out[(size_t)n * W + lane] = v;
    }
}

// fused pos+neg scorer: 8 lanes per edge, float4 slices of 32-wide h rows
__global__ __launch_bounds__(256) void score2_kernel(const float* __restrict__ h,
                                                     const int* __restrict__ sA,
                                                     const int* __restrict__ dA,
                                                     const int* __restrict__ sB,
                                                     const int* __restrict__ dB,
                                                     const float* __restrict__ wrel,
                                                     float* __restrict__ outA,
                                                     float* __restrict__ outB,
                                                     int EA, int EB) {
    const int lj = threadIdx.x & 7;
    const size_t grp = ((size_t)blockIdx.x * blockDim.x + threadIdx.x) >> 3;
    const size_t ngrp = ((size_t)gridDim.x * blockDim.x) >> 3;
    const float4 w = *(const float4*)(wrel + lj * 4);
    const size_t total = (size_t)EA + (size_t)EB;
    for (size_t e = grp; e < total; e += ngrp) {
        int s, d; float* o;
        if (e < (size_t)EA) { s = sA[e]; d = dA[e]; o = outA + e; }
        else { const size_t e2 = e - EA; s = sB[e2]; d = dB[e2]; o = outB + e2; }
        const float4 hs = *(const float4*)(h + (size_t)s * 32 + lj * 4);
        const float4 hd = *(const float4*)(h + (size_t)d * 32 + lj * 4);
        float p = hs.x * w.x * hd.x + hs.y * w.y * hd.y +
                  hs.z * w.z * hd.z + hs.w * w.w * hd.w;
        p += __shfl_xor(p, 1, 64);
        p += __shfl_xor(p, 2, 64);
        p += __shfl_xor(p, 4, 64);
        if (lj == 0) *o = p;
    }
}

extern "C" void kernel_launch(void* const* d_in, const int* in_sizes, int n_in,
                              void* d_out, int out_size, void* d_ws, size_t ws_size,
                              hipStream_t stream) {
    const float* feat_drug    = (const float*)d_in[0];
    const int*   dd_src       = (const int*)d_in[2];
    const int*   dd_dst       = (const int*)d_in[3];
    const int*   neg_src      = (const int*)d_in[8];
    const int*   neg_dst      = (const int*)d_in[9];
    const float* W1_dd        = (const float*)d_in[10];
    const float* W1_self_drug = (const float*)d_in[13];
    const float* b1           = (const float*)d_in[15];
    const float* W2_dd        = (const float*)d_in[16];
    const float* W2_self_drug = (const float*)d_in[19];
    const float* b2           = (const float*)d_in[21];
    const float* w_rel        = (const float*)d_in[22];

    const int N  = in_sizes[0] / 128;  // 20000 drugs
    const int E  = in_sizes[2];        // 1.5M dd edges
    const int EN = in_sizes[8];        // 1.5M neg edges
    const int CHUNK = (E + NPART - 1) / NPART;
    const int M8 = NPART * N;

    // workspace layout (4-byte elements)
    char* ws = (char*)d_ws;
    int*   deg8    = (int*)ws;                         ws += (size_t)M8 * 4;
    int*   off8    = (int*)ws;                         ws += (size_t)M8 * 4;
    int*   cursor8 = (int*)ws;                         ws += (size_t)M8 * 4;
    int*   csr_src = (int*)ws;                         ws += (size_t)E * 4;
    float* msg1    = (float*)ws;                       ws += (size_t)N * 64 * 4;
    float* self1   = (float*)ws;                       ws += (size_t)N * 64 * 4;
    float* h1      = (float*)ws;                       ws += (size_t)N * 64 * 4;
    float* msg2    = (float*)ws;                       ws += (size_t)N * 32 * 4;
    float* self2   = (float*)ws;                       ws += (size_t)N * 32 * 4;
    float* h2      = (float*)ws;                       ws += (size_t)N * 32 * 4;

    float* pos = (float*)d_out;
    float* neg = pos + E;

    hipMemsetAsync(deg8, 0, (size_t)M8 * sizeof(int), stream);

    // ---- CSR-by-dst build (edge-chunk partitioned, XCD-private regions) ----
    degree8_kernel<<<1024, 256, 0, stream>>>(dd_dst, deg8, E, CHUNK, N);
    scan8_kernel<<<NPART, 1024, 0, stream>>>(deg8, off8, cursor8, N, CHUNK);
    fill8_kernel<<<1024, 256, 0, stream>>>(dd_src, dd_dst, cursor8, csr_src, E, CHUNK, N);

    // ---- layer 1: register-weight GEMMs (no LDS) ----
    gemm_reg_kernel<128><<<512, 256, 0, stream>>>(feat_drug, W1_dd, msg1, N);
    gemm_reg_kernel<128><<<512, 256, 0, stream>>>(feat_drug, W1_self_drug, self1, N);
    gather_combine_kernel<64, true><<<(N + 3) / 4, 256, 0, stream>>>(
        msg1, csr_src, off8, cursor8, self1, b1, h1, N);

    // ---- layer 2: fused dual-matrix register GEMM ----
    gemm2_reg_kernel<<<512, 256, 0, stream>>>(h1, W2_dd, W2_self_drug, msg2, self2, N);
    gather_combine_kernel<32, false><<<(N + 7) / 8, 256, 0, stream>>>(
        msg2, csr_src, off8, cursor8, self2, b2, h2, N);

    // ---- scorer (pos + neg fused) ----
    score2_kernel<<<4096, 256, 0, stream>>>(h2, dd_src, dd_dst, neg_src, neg_dst,
                                            w_rel, pos, neg, E, EN);
}

// Round 8
// 396.762 us; speedup vs baseline: 1.9015x; 1.0282x over previous
//
#include <hip/hip_runtime.h>

// ---------------------------------------------------------------------------
// Drug-path-only GNN (gene path is dead code w.r.t. outputs).
// Round 8: bf16 gather tables. Round-7 profile: gather_combine<64> fetched
// 74.5MB HBM for a 5MB msg table -- random 256B-row gathers against a table
// that doesn't fit one XCD's 4MB L2 (20% miss x 384MB L2 traffic = 77MB).
// msg1/msg2/h2 stored as bf16 (2.5/1.25/1.25MB -> L2-resident), csr_src as
// ushort (N<65536). fp32 accumulation everywhere; bf16 adds ~1e-3 absmax
// against a 2.2e-2 threshold.
// ---------------------------------------------------------------------------

#define NPART 8

__device__ inline float bf2f(unsigned short b) {
    union { float f; unsigned u; } c; c.u = (unsigned)b << 16; return c.f;
}
__device__ inline unsigned short f2bf(float x) {
    union { float f; unsigned u; } c; c.f = x;
    unsigned r = c.u + 0x7FFF + ((c.u >> 16) & 1);
    return (unsigned short)(r >> 16);
}

// out[m][n] = bf16(sum_k A[m][k]*W[k][n]); KOUT==64; weights in VGPRs
template<int KIN>
__global__ __launch_bounds__(256) void gemm_reg_kernel(const float* __restrict__ A,
                                                       const float* __restrict__ W,
                                                       unsigned short* __restrict__ out,
                                                       int M) {
    const int lane = threadIdx.x & 63;
    const int gwave = blockIdx.x * (blockDim.x >> 6) + (threadIdx.x >> 6);
    const int nwave = gridDim.x * (blockDim.x >> 6);
    float w[KIN];
#pragma unroll
    for (int k = 0; k < KIN; ++k) w[k] = W[k * 64 + lane];
    for (int m0 = gwave * 2; m0 < M; m0 += nwave * 2) {
        const int mu = __builtin_amdgcn_readfirstlane(m0);
        const float* a0 = A + (size_t)mu * KIN;
        const float* a1 = a0 + KIN;
        const bool two = (mu + 1) < M;
        float acc0 = 0.0f, acc1 = 0.0f;
#pragma unroll
        for (int k = 0; k < KIN; ++k) {
            const float av0 = a0[k];
            const float av1 = two ? a1[k] : 0.0f;
            acc0 = fmaf(av0, w[k], acc0);
            acc1 = fmaf(av1, w[k], acc1);
        }
        out[(size_t)mu * 64 + lane] = f2bf(acc0);
        if (two) out[(size_t)(mu + 1) * 64 + lane] = f2bf(acc1);
    }
}

// layer-2 pair: KIN=64, KOUT=32. Lanes 0..31 -> Wa cols, lanes 32..63 -> Wb.
__global__ __launch_bounds__(256) void gemm2_reg_kernel(const float* __restrict__ A,
                                                        const float* __restrict__ Wa,
                                                        const float* __restrict__ Wb,
                                                        unsigned short* __restrict__ out_a,
                                                        unsigned short* __restrict__ out_b,
                                                        int M) {
    const int lane = threadIdx.x & 63;
    const int col = lane & 31;
    const float* Wm = (lane < 32) ? Wa : Wb;
    unsigned short* om = (lane < 32) ? out_a : out_b;
    const int gwave = blockIdx.x * (blockDim.x >> 6) + (threadIdx.x >> 6);
    const int nwave = gridDim.x * (blockDim.x >> 6);
    float w[64];
#pragma unroll
    for (int k = 0; k < 64; ++k) w[k] = Wm[k * 32 + col];
    for (int m0 = gwave * 2; m0 < M; m0 += nwave * 2) {
        const int mu = __builtin_amdgcn_readfirstlane(m0);
        const float* a0 = A + (size_t)mu * 64;
        const float* a1 = a0 + 64;
        const bool two = (mu + 1) < M;
        float acc0 = 0.0f, acc1 = 0.0f;
#pragma unroll
        for (int k = 0; k < 64; ++k) {
            const float av0 = a0[k];
            const float av1 = two ? a1[k] : 0.0f;
            acc0 = fmaf(av0, w[k], acc0);
            acc1 = fmaf(av1, w[k], acc1);
        }
        om[(size_t)mu * 32 + col] = f2bf(acc0);
        if (two) om[(size_t)(mu + 1) * 32 + col] = f2bf(acc1);
    }
}

// per-edge-chunk degree histogram into partition-private deg8[p][n]
__global__ __launch_bounds__(256) void degree8_kernel(const int* __restrict__ dst,
                                                      int* __restrict__ deg8,
                                                      int E, int chunk, int N) {
    const int p = blockIdx.x & (NPART - 1);
    const int lo = p * chunk;
    const int hi = min(lo + chunk, E);
    int* __restrict__ deg = deg8 + (size_t)p * N;
    const int bip = blockIdx.x >> 3;
    const int stride = (gridDim.x >> 3) * 256;
    for (int e = lo + bip * 256 + threadIdx.x; e < hi; e += stride)
        atomicAdd(&deg[dst[e]], 1);
}

// 8 independent within-partition scans; block p's base offset = p*chunk.
__global__ __launch_bounds__(1024) void scan8_kernel(const int* __restrict__ deg8,
                                                     int* __restrict__ off8,
                                                     int* __restrict__ cursor8,
                                                     int N, int chunk) {
    const int p = blockIdx.x;
    const int base = p * chunk;
    const int* __restrict__ deg = deg8 + (size_t)p * N;
    int* __restrict__ off = off8 + (size_t)p * N;
    int* __restrict__ cur = cursor8 + (size_t)p * N;
    __shared__ int part[1024];
    const int t = threadIdx.x;
    const int per = (N + 1023) / 1024;
    const int beg = t * per;
    const int end = min(beg + per, N);
    int s = 0;
    for (int i = beg; i < end; ++i) s += deg[i];
    part[t] = s;
    __syncthreads();
    for (int d = 1; d < 1024; d <<= 1) {
        int v = (t >= d) ? part[t - d] : 0;
        __syncthreads();
        part[t] += v;
        __syncthreads();
    }
    int run = base + ((t == 0) ? 0 : part[t - 1]);
    for (int i = beg; i < end; ++i) { off[i] = run; cur[i] = run; run += deg[i]; }
}

// edge-chunk-partitioned bucket fill into partition-private CSR segments
__global__ __launch_bounds__(256) void fill8_kernel(const int* __restrict__ src,
                                                    const int* __restrict__ dst,
                                                    int* __restrict__ cursor8,
                                                    unsigned short* __restrict__ csr_src,
                                                    int E, int chunk, int N) {
    const int p = blockIdx.x & (NPART - 1);
    const int lo = p * chunk;
    const int hi = min(lo + chunk, E);
    int* __restrict__ cursor = cursor8 + (size_t)p * N;
    const int bip = blockIdx.x >> 3;
    const int stride = (gridDim.x >> 3) * 256;
    for (int e = lo + bip * 256 + threadIdx.x; e < hi; e += stride) {
        const int d = dst[e];
        const int s = src[e];
        const int pos = atomicAdd(&cursor[d], 1);
        csr_src[pos] = (unsigned short)s;
    }
}

// One W-lane group per dst node: loop 8 partition sub-segments over bf16 msg,
// fp32 accumulate, fused mean+self+bias(+relu). OBF: write bf16 output.
template<int W, bool RELU, bool OBF>
__global__ __launch_bounds__(256) void gather_combine_kernel(
        const unsigned short* __restrict__ msg,
        const unsigned short* __restrict__ csr_src,
        const int* __restrict__ off8, const int* __restrict__ end8,
        const unsigned short* __restrict__ selfb, const float* __restrict__ b,
        void* __restrict__ out_, int N) {
    const int GRP = 256 / W;
    const int g = threadIdx.x / W;
    const int lane = threadIdx.x % W;
    const float bk = b[lane];
    for (int n = blockIdx.x * GRP + g; n < N; n += gridDim.x * GRP) {
        float acc = 0.0f;
        int cnt = 0;
        for (int p = 0; p < NPART; ++p) {
            const int beg = off8[(size_t)p * N + n];
            const int end = end8[(size_t)p * N + n];
            cnt += end - beg;
            int i = beg;
            for (; i + 4 <= end; i += 4) {
                const int s0 = csr_src[i], s1 = csr_src[i + 1];
                const int s2 = csr_src[i + 2], s3 = csr_src[i + 3];
                const float v0 = bf2f(msg[(size_t)s0 * W + lane]);
                const float v1 = bf2f(msg[(size_t)s1 * W + lane]);
                const float v2 = bf2f(msg[(size_t)s2 * W + lane]);
                const float v3 = bf2f(msg[(size_t)s3 * W + lane]);
                acc += (v0 + v1) + (v2 + v3);
            }
            for (; i < end; ++i) acc += bf2f(msg[(size_t)csr_src[i] * W + lane]);
        }
        const float d = (cnt > 0) ? (float)cnt : 1.0f;
        float v = acc / d + bf2f(selfb[(size_t)n * W + lane]) + bk;
        if (RELU) v = fmaxf(v, 0.0f);
        if (OBF) ((unsigned short*)out_)[(size_t)n * W + lane] = f2bf(v);
        else     ((float*)out_)[(size_t)n * W + lane] = v;
    }
}

// fused pos+neg scorer over bf16 h: 8 lanes/edge, ushort4 (8B) slices of 64B rows
__global__ __launch_bounds__(256) void score2_kernel(const unsigned short* __restrict__ h,
                                                     const int* __restrict__ sA,
                                                     const int* __restrict__ dA,
                                                     const int* __restrict__ sB,
                                                     const int* __restrict__ dB,
                                                     const float* __restrict__ wrel,
                                                     float* __restrict__ outA,
                                                     float* __restrict__ outB,
                                                     int EA, int EB) {
    const int lj = threadIdx.x & 7;
    const size_t grp = ((size_t)blockIdx.x * blockDim.x + threadIdx.x) >> 3;
    const size_t ngrp = ((size_t)gridDim.x * blockDim.x) >> 3;
    const float4 w = *(const float4*)(wrel + lj * 4);
    const size_t total = (size_t)EA + (size_t)EB;
    for (size_t e = grp; e < total; e += ngrp) {
        int s, d; float* o;
        if (e < (size_t)EA) { s = sA[e]; d = dA[e]; o = outA + e; }
        else { const size_t e2 = e - EA; s = sB[e2]; d = dB[e2]; o = outB + e2; }
        const ushort4 hs = *(const ushort4*)(h + (size_t)s * 32 + lj * 4);
        const ushort4 hd = *(const ushort4*)(h + (size_t)d * 32 + lj * 4);
        float p = bf2f(hs.x) * w.x * bf2f(hd.x) + bf2f(hs.y) * w.y * bf2f(hd.y) +
                  bf2f(hs.z) * w.z * bf2f(hd.z) + bf2f(hs.w) * w.w * bf2f(hd.w);
        p += __shfl_xor(p, 1, 64);
        p += __shfl_xor(p, 2, 64);
        p += __shfl_xor(p, 4, 64);
        if (lj == 0) *o = p;
    }
}

extern "C" void kernel_launch(void* const* d_in, const int* in_sizes, int n_in,
                              void* d_out, int out_size, void* d_ws, size_t ws_size,
                              hipStream_t stream) {
    const float* feat_drug    = (const float*)d_in[0];
    const int*   dd_src       = (const int*)d_in[2];
    const int*   dd_dst       = (const int*)d_in[3];
    const int*   neg_src      = (const int*)d_in[8];
    const int*   neg_dst      = (const int*)d_in[9];
    const float* W1_dd        = (const float*)d_in[10];
    const float* W1_self_drug = (const float*)d_in[13];
    const float* b1           = (const float*)d_in[15];
    const float* W2_dd        = (const float*)d_in[16];
    const float* W2_self_drug = (const float*)d_in[19];
    const float* b2           = (const float*)d_in[21];
    const float* w_rel        = (const float*)d_in[22];

    const int N  = in_sizes[0] / 128;  // 20000 drugs  (< 65536: ushort csr ok)
    const int E  = in_sizes[2];        // 1.5M dd edges
    const int EN = in_sizes[8];        // 1.5M neg edges
    const int CHUNK = (E + NPART - 1) / NPART;
    const int M8 = NPART * N;

    // workspace layout
    char* ws = (char*)d_ws;
    int*            deg8    = (int*)ws;            ws += (size_t)M8 * 4;
    int*            off8    = (int*)ws;            ws += (size_t)M8 * 4;
    int*            cursor8 = (int*)ws;            ws += (size_t)M8 * 4;
    unsigned short* csr16   = (unsigned short*)ws; ws += (size_t)E * 2;
    ws = (char*)(((size_t)ws + 3) & ~(size_t)3);
    unsigned short* msg1    = (unsigned short*)ws; ws += (size_t)N * 64 * 2;
    unsigned short* self1   = (unsigned short*)ws; ws += (size_t)N * 64 * 2;
    unsigned short* msg2    = (unsigned short*)ws; ws += (size_t)N * 32 * 2;
    unsigned short* self2   = (unsigned short*)ws; ws += (size_t)N * 32 * 2;
    unsigned short* h2      = (unsigned short*)ws; ws += (size_t)N * 32 * 2;
    ws = (char*)(((size_t)ws + 3) & ~(size_t)3);
    float*          h1      = (float*)ws;          ws += (size_t)N * 64 * 4;

    float* pos = (float*)d_out;
    float* neg = pos + E;

    hipMemsetAsync(deg8, 0, (size_t)M8 * sizeof(int), stream);

    // ---- CSR-by-dst build (edge-chunk partitioned, XCD-private regions) ----
    degree8_kernel<<<1024, 256, 0, stream>>>(dd_dst, deg8, E, CHUNK, N);
    scan8_kernel<<<NPART, 1024, 0, stream>>>(deg8, off8, cursor8, N, CHUNK);
    fill8_kernel<<<1024, 256, 0, stream>>>(dd_src, dd_dst, cursor8, csr16, E, CHUNK, N);

    // ---- layer 1: register-weight GEMMs -> bf16 msg/self ----
    gemm_reg_kernel<128><<<512, 256, 0, stream>>>(feat_drug, W1_dd, msg1, N);
    gemm_reg_kernel<128><<<512, 256, 0, stream>>>(feat_drug, W1_self_drug, self1, N);
    gather_combine_kernel<64, true, false><<<(N + 3) / 4, 256, 0, stream>>>(
        msg1, csr16, off8, cursor8, self1, b1, h1, N);

    // ---- layer 2: fused dual-matrix register GEMM -> bf16 ----
    gemm2_reg_kernel<<<512, 256, 0, stream>>>(h1, W2_dd, W2_self_drug, msg2, self2, N);
    gather_combine_kernel<32, false, true><<<(N + 7) / 8, 256, 0, stream>>>(
        msg2, csr16, off8, cursor8, self2, b2, h2, N);

    // ---- scorer (pos + neg fused, bf16 h2) ----
    score2_kernel<<<4096, 256, 0, stream>>>(h2, dd_src, dd_dst, neg_src, neg_dst,
                                            w_rel, pos, neg, E, EN);
}